// Round 3
// baseline (591.560 us; speedup 1.0000x reference)
//
#include <hip/hip_runtime.h>

typedef _Float16 half8   __attribute__((ext_vector_type(8)));
typedef __fp16   half2_t __attribute__((ext_vector_type(2)));
typedef float    floatx4 __attribute__((ext_vector_type(4)));

// ---------------------------------------------------------------------------
// Kernel 1: sort each (n,c) 1024-vector descending, write fp16 to workspace.
// One wave per vector, 16 elems/lane, register bitonic (unchanged this round).
// ws layout: z[c][n][x], row = c*256 + n
// ---------------------------------------------------------------------------
__global__ __launch_bounds__(256) void sort_kernel(const float* __restrict__ x,
                                                   unsigned short* __restrict__ zs) {
  const int wave = threadIdx.x >> 6;
  const int lane = threadIdx.x & 63;
  const int vec  = (blockIdx.x << 2) + wave;     // vec = n*64 + c

  const float* src = x + ((size_t)vec << 10) + (lane << 4);
  float v[16];
#pragma unroll
  for (int r4 = 0; r4 < 4; ++r4) {
    float4 f = *reinterpret_cast<const float4*>(src + (r4 << 2));
    v[r4 * 4 + 0] = f.x; v[r4 * 4 + 1] = f.y;
    v[r4 * 4 + 2] = f.z; v[r4 * 4 + 3] = f.w;
  }

  auto CEs = [&](int a, int b, bool desc) {
    float lo = fminf(v[a], v[b]);
    float hi = fmaxf(v[a], v[b]);
    v[a] = desc ? hi : lo;
    v[b] = desc ? lo : hi;
  };

#pragma unroll
  for (int r = 0; r < 16; r += 2) CEs(r, r + 1, (r & 2) == 0);
#pragma unroll
  for (int r = 0; r < 16; ++r) if ((r & 2) == 0) CEs(r, r | 2, (r & 4) == 0);
#pragma unroll
  for (int r = 0; r < 16; r += 2) CEs(r, r + 1, (r & 4) == 0);
#pragma unroll
  for (int r = 0; r < 16; ++r) if ((r & 4) == 0) CEs(r, r | 4, (r & 8) == 0);
#pragma unroll
  for (int r = 0; r < 16; ++r) if ((r & 2) == 0) CEs(r, r | 2, (r & 8) == 0);
#pragma unroll
  for (int r = 0; r < 16; r += 2) CEs(r, r + 1, (r & 8) == 0);

#pragma unroll
  for (int k = 16; k <= 1024; k <<= 1) {
    const bool d = (lane & (k >> 4)) == 0;
#pragma unroll
    for (int j = k >> 1; j >= 16; j >>= 1) {
      const int dl = j >> 4;
      const bool keepmax = (((lane & dl) == 0) == d);
#pragma unroll
      for (int r = 0; r < 16; ++r) {
        float p = __shfl_xor(v[r], dl, 64);
        v[r] = keepmax ? fmaxf(v[r], p) : fminf(v[r], p);
      }
    }
#pragma unroll
    for (int j = 8; j >= 1; j >>= 1)
#pragma unroll
      for (int r = 0; r < 16; ++r)
        if ((r & j) == 0) CEs(r, r | j, d);
  }

  const int n = vec >> 6, c = vec & 63;
  union { half2_t h2[8]; uint4 u[2]; } pk;
#pragma unroll
  for (int r = 0; r < 8; ++r)
    pk.h2[r] = __builtin_amdgcn_cvt_pkrtz(v[2 * r], v[2 * r + 1]);
  uint4* dst = reinterpret_cast<uint4*>(zs + ((size_t)(c * 256 + n) << 10) + (lane << 4));
  dst[0] = pk.u[0];
  dst[1] = pk.u[1];
}

// ---------------------------------------------------------------------------
// Kernel 2: barrier-free, LDS-free per-channel GEMM.
// grid = (16 n-tiles, 64 channels), block = 256 thr = 4 waves.
// Each wave owns a 64x64 tile: 4x4 mfma_f32_16x16x32_f16, acc 64 VGPRs.
// A (z, fp16): lane loads 16B frag chunks straight from global.
// B (W, f32):  lane loads 2x16B, converts to fp16 in-register (cvt_pkrtz).
// 2-deep register pipeline (load k+1 while mfma k), zero __syncthreads.
// 4 waves/block share the same 64 W columns -> W reuse via L1 (8KB/stage).
// Frag layouts (verified in R2): A[m=lane&15][k=q*8+j], B sym.,
// D row=q*4+reg, col=lane&15.
// ---------------------------------------------------------------------------
__global__ __launch_bounds__(256) void gemm_kernel(const unsigned short* __restrict__ zs,
                                                   const float* __restrict__ W,
                                                   const float* __restrict__ bias,
                                                   float* __restrict__ out) {
  const int c    = blockIdx.y;
  const int n0   = blockIdx.x << 6;            // 64-col slab
  const int m0   = (threadIdx.x >> 6) << 6;    // wave -> 64-row slab
  const int lane = threadIdx.x & 63;
  const int lr   = lane & 15;
  const int q    = lane >> 4;

  const unsigned short* zc = zs + (((size_t)c * 256) << 10);
  const float*          wc = W + ((size_t)c << 20);

  const uint4* pz[4];   // advance 4 uint4 (=32 halves) per k-step
  const uint4* pw[4];   // advance 8 uint4 (=32 floats) per k-step
#pragma unroll
  for (int mi = 0; mi < 4; ++mi)
    pz[mi] = reinterpret_cast<const uint4*>(zc + (((size_t)(m0 + mi * 16 + lr)) << 10) + (q << 3));
#pragma unroll
  for (int ni = 0; ni < 4; ++ni)
    pw[ni] = reinterpret_cast<const uint4*>(wc + (((size_t)(n0 + ni * 16 + lr)) << 10) + (q << 3));

  floatx4 acc[4][4] = {};
  union U { uint4 u; half8 h; float4 f; };

  half8 a0[4], a1[4];
  uint4 w0a[4], w0b[4], w1a[4], w1b[4];

  auto loadA = [&](half8* a) {
#pragma unroll
    for (int mi = 0; mi < 4; ++mi) {
      U t; t.u = pz[mi][0];
      pz[mi] += 4;
      a[mi] = t.h;
    }
  };
  auto loadW = [&](uint4* wa, uint4* wb) {
#pragma unroll
    for (int ni = 0; ni < 4; ++ni) {
      wa[ni] = pw[ni][0];
      wb[ni] = pw[ni][1];
      pw[ni] += 8;
    }
  };
  auto cvtB = [](const uint4& ua, const uint4& ub) -> half8 {
    U fa, fb; fa.u = ua; fb.u = ub;
    union { half2_t h2[4]; half8 h8; } pk;
    pk.h2[0] = __builtin_amdgcn_cvt_pkrtz(fa.f.x, fa.f.y);
    pk.h2[1] = __builtin_amdgcn_cvt_pkrtz(fa.f.z, fa.f.w);
    pk.h2[2] = __builtin_amdgcn_cvt_pkrtz(fb.f.x, fb.f.y);
    pk.h2[3] = __builtin_amdgcn_cvt_pkrtz(fb.f.z, fb.f.w);
    return pk.h8;
  };

  auto compute = [&](half8* a, uint4* wa, uint4* wb) {
#pragma unroll
    for (int ni = 0; ni < 4; ++ni) {
      const half8 b = cvtB(wa[ni], wb[ni]);
#pragma unroll
      for (int mi = 0; mi < 4; ++mi)
        acc[mi][ni] = __builtin_amdgcn_mfma_f32_16x16x32_f16(a[mi], b, acc[mi][ni], 0, 0, 0);
    }
  };

  loadA(a0); loadW(w0a, w0b);                 // k-tile 0
  for (int kb = 0; kb < 1024; kb += 64) {
    loadA(a1); loadW(w1a, w1b);               // k-tile kb+32
    compute(a0, w0a, w0b);
    if (kb + 64 < 1024) { loadA(a0); loadW(w0a, w0b); }   // k-tile kb+64
    compute(a1, w1a, w1b);
  }

  // epilogue: bias + sigmoid, out[n][c][o] fp32
#pragma unroll
  for (int ni = 0; ni < 4; ++ni) {
    const int col = n0 + ni * 16 + lr;
    const float bv = bias[(c << 10) + col];
#pragma unroll
    for (int mi = 0; mi < 4; ++mi) {
      const int row0 = m0 + mi * 16 + q * 4;
#pragma unroll
      for (int rr = 0; rr < 4; ++rr) {
        const float y = acc[mi][ni][rr] + bv;
        const float s = __builtin_amdgcn_rcpf(1.0f + __expf(-y));
        out[(((size_t)(row0 + rr) << 6) + c) * 1024 + col] = s;
      }
    }
  }
}

extern "C" void kernel_launch(void* const* d_in, const int* in_sizes, int n_in,
                              void* d_out, int out_size, void* d_ws, size_t ws_size,
                              hipStream_t stream) {
  const float* x    = (const float*)d_in[0];   // (256, 64, 32, 32) f32
  const float* W    = (const float*)d_in[1];   // (64, 1024, 1024) f32
  const float* bias = (const float*)d_in[2];   // (64, 1024) f32
  float*       out  = (float*)d_out;           // (256, 64, 1024) f32
  unsigned short* zs = (unsigned short*)d_ws;  // 16384*1024 fp16 = 33.5 MB

  sort_kernel<<<4096, 256, 0, stream>>>(x, zs);
  gemm_kernel<<<dim3(16, 64), 256, 0, stream>>>(zs, W, bias, out);
}

// Round 4
// 567.527 us; speedup vs baseline: 1.0423x; 1.0423x over previous
//
#include <hip/hip_runtime.h>

typedef _Float16 half8   __attribute__((ext_vector_type(8)));
typedef __fp16   half2_t __attribute__((ext_vector_type(2)));
typedef float    floatx4 __attribute__((ext_vector_type(4)));

// ---------------------------------------------------------------------------
// Kernel 1: sort each (n,c) 1024-vector descending, write fp16 to workspace.
// One wave per vector, 16 elems/lane, register bitonic (unchanged).
// ws layout: z[c][n][x], row = c*256 + n
// ---------------------------------------------------------------------------
__global__ __launch_bounds__(256) void sort_kernel(const float* __restrict__ x,
                                                   unsigned short* __restrict__ zs) {
  const int wave = threadIdx.x >> 6;
  const int lane = threadIdx.x & 63;
  const int vec  = (blockIdx.x << 2) + wave;     // vec = n*64 + c

  const float* src = x + ((size_t)vec << 10) + (lane << 4);
  float v[16];
#pragma unroll
  for (int r4 = 0; r4 < 4; ++r4) {
    float4 f = *reinterpret_cast<const float4*>(src + (r4 << 2));
    v[r4 * 4 + 0] = f.x; v[r4 * 4 + 1] = f.y;
    v[r4 * 4 + 2] = f.z; v[r4 * 4 + 3] = f.w;
  }

  auto CEs = [&](int a, int b, bool desc) {
    float lo = fminf(v[a], v[b]);
    float hi = fmaxf(v[a], v[b]);
    v[a] = desc ? hi : lo;
    v[b] = desc ? lo : hi;
  };

#pragma unroll
  for (int r = 0; r < 16; r += 2) CEs(r, r + 1, (r & 2) == 0);
#pragma unroll
  for (int r = 0; r < 16; ++r) if ((r & 2) == 0) CEs(r, r | 2, (r & 4) == 0);
#pragma unroll
  for (int r = 0; r < 16; r += 2) CEs(r, r + 1, (r & 4) == 0);
#pragma unroll
  for (int r = 0; r < 16; ++r) if ((r & 4) == 0) CEs(r, r | 4, (r & 8) == 0);
#pragma unroll
  for (int r = 0; r < 16; ++r) if ((r & 2) == 0) CEs(r, r | 2, (r & 8) == 0);
#pragma unroll
  for (int r = 0; r < 16; r += 2) CEs(r, r + 1, (r & 8) == 0);

#pragma unroll
  for (int k = 16; k <= 1024; k <<= 1) {
    const bool d = (lane & (k >> 4)) == 0;
#pragma unroll
    for (int j = k >> 1; j >= 16; j >>= 1) {
      const int dl = j >> 4;
      const bool keepmax = (((lane & dl) == 0) == d);
#pragma unroll
      for (int r = 0; r < 16; ++r) {
        float p = __shfl_xor(v[r], dl, 64);
        v[r] = keepmax ? fmaxf(v[r], p) : fminf(v[r], p);
      }
    }
#pragma unroll
    for (int j = 8; j >= 1; j >>= 1)
#pragma unroll
      for (int r = 0; r < 16; ++r)
        if ((r & j) == 0) CEs(r, r | j, d);
  }

  const int n = vec >> 6, c = vec & 63;
  union { half2_t h2[8]; uint4 u[2]; } pk;
#pragma unroll
  for (int r = 0; r < 8; ++r)
    pk.h2[r] = __builtin_amdgcn_cvt_pkrtz(v[2 * r], v[2 * r + 1]);
  uint4* dst = reinterpret_cast<uint4*>(zs + ((size_t)(c * 256 + n) << 10) + (lane << 4));
  dst[0] = pk.u[0];
  dst[1] = pk.u[1];
}

// ---------------------------------------------------------------------------
// Kernel 2: barrier-free, LDS-free per-channel GEMM — depth-2 register
// pipeline. __launch_bounds__(256,2) grants ~256 VGPR/wave so the compiler
// can keep both buffer sets live (R3 failure: at default bounds it allocated
// 112 VGPR and serialized the loads).
// grid = (16 n-slabs, 64 channels), block = 4 waves, wave tile 64x64.
// Per 32-k tile: A = 4x dwordx4 (z fp16, frag-native), B = 8x dwordx4
// (W f32, converted via cvt_pkrtz at consume time).
// Steady state: compute tile t, tile t+1 loaded, tile t+2 issuing.
// ---------------------------------------------------------------------------
__global__ __launch_bounds__(256, 2) void gemm_kernel(const unsigned short* __restrict__ zs,
                                                      const float* __restrict__ W,
                                                      const float* __restrict__ bias,
                                                      float* __restrict__ out) {
  const int c    = blockIdx.y;
  const int n0   = blockIdx.x << 6;            // 64-col (out-feature) slab
  const int m0   = (threadIdx.x >> 6) << 6;    // wave -> 64-row (batch) slab
  const int lane = threadIdx.x & 63;
  const int lr   = lane & 15;
  const int q    = lane >> 4;

  const unsigned short* zc = zs + (((size_t)c * 256) << 10);
  const float*          wc = W + ((size_t)c << 20);

  const uint4* pz[4];   // advance 2 uint4 (=16 halves... 32 halves/row-step) per k32
  const uint4* pw[4];   // advance 8 uint4 (=32 floats) per k32
#pragma unroll
  for (int mi = 0; mi < 4; ++mi)
    pz[mi] = reinterpret_cast<const uint4*>(zc + (((size_t)(m0 + mi * 16 + lr)) << 10) + (q << 3));
#pragma unroll
  for (int ni = 0; ni < 4; ++ni)
    pw[ni] = reinterpret_cast<const uint4*>(wc + (((size_t)(n0 + ni * 16 + lr)) << 10) + (q << 3));

  floatx4 acc[4][4] = {};
  union U { uint4 u; half8 h; float4 f; };

  // two pipeline buffer sets
  half8 a0[4], a1[4];
  uint4 w0[8], w1[8];

  auto load0 = [&]() {
#pragma unroll
    for (int mi = 0; mi < 4; ++mi) { U t; t.u = pz[mi][0]; pz[mi] += 4; a0[mi] = t.h; }
#pragma unroll
    for (int ni = 0; ni < 4; ++ni) { w0[2 * ni] = pw[ni][0]; w0[2 * ni + 1] = pw[ni][1]; pw[ni] += 8; }
  };
  auto load1 = [&]() {
#pragma unroll
    for (int mi = 0; mi < 4; ++mi) { U t; t.u = pz[mi][0]; pz[mi] += 4; a1[mi] = t.h; }
#pragma unroll
    for (int ni = 0; ni < 4; ++ni) { w1[2 * ni] = pw[ni][0]; w1[2 * ni + 1] = pw[ni][1]; pw[ni] += 8; }
  };

  auto cvtB = [](const uint4& ua, const uint4& ub) -> half8 {
    U fa, fb; fa.u = ua; fb.u = ub;
    union { half2_t h2[4]; half8 h8; } pk;
    pk.h2[0] = __builtin_amdgcn_cvt_pkrtz(fa.f.x, fa.f.y);
    pk.h2[1] = __builtin_amdgcn_cvt_pkrtz(fa.f.z, fa.f.w);
    pk.h2[2] = __builtin_amdgcn_cvt_pkrtz(fb.f.x, fb.f.y);
    pk.h2[3] = __builtin_amdgcn_cvt_pkrtz(fb.f.z, fb.f.w);
    return pk.h8;
  };

  auto compute0 = [&]() {
#pragma unroll
    for (int ni = 0; ni < 4; ++ni) {
      const half8 b = cvtB(w0[2 * ni], w0[2 * ni + 1]);
#pragma unroll
      for (int mi = 0; mi < 4; ++mi)
        acc[mi][ni] = __builtin_amdgcn_mfma_f32_16x16x32_f16(a0[mi], b, acc[mi][ni], 0, 0, 0);
    }
  };
  auto compute1 = [&]() {
#pragma unroll
    for (int ni = 0; ni < 4; ++ni) {
      const half8 b = cvtB(w1[2 * ni], w1[2 * ni + 1]);
#pragma unroll
      for (int mi = 0; mi < 4; ++mi)
        acc[mi][ni] = __builtin_amdgcn_mfma_f32_16x16x32_f16(a1[mi], b, acc[mi][ni], 0, 0, 0);
    }
  };

  // 32 k-tiles of 32. Prologue: tiles 0,1 in flight.
  load0();                 // tile 0
  load1();                 // tile 1
#pragma unroll 1
  for (int t = 0; t < 30; t += 2) {
    compute0(); load0();   // compute tile t,   issue tile t+2
    compute1(); load1();   // compute tile t+1, issue tile t+3
  }
  compute0();              // tile 30
  compute1();              // tile 31

  // epilogue: bias + sigmoid, out[n][c][o] fp32
#pragma unroll
  for (int ni = 0; ni < 4; ++ni) {
    const int col = n0 + ni * 16 + lr;
    const float bv = bias[(c << 10) + col];
#pragma unroll
    for (int mi = 0; mi < 4; ++mi) {
      const int row0 = m0 + mi * 16 + q * 4;
#pragma unroll
      for (int rr = 0; rr < 4; ++rr) {
        const float y = acc[mi][ni][rr] + bv;
        const float s = __builtin_amdgcn_rcpf(1.0f + __expf(-y));
        out[(((size_t)(row0 + rr) << 6) + c) * 1024 + col] = s;
      }
    }
  }
}

extern "C" void kernel_launch(void* const* d_in, const int* in_sizes, int n_in,
                              void* d_out, int out_size, void* d_ws, size_t ws_size,
                              hipStream_t stream) {
  const float* x    = (const float*)d_in[0];   // (256, 64, 32, 32) f32
  const float* W    = (const float*)d_in[1];   // (64, 1024, 1024) f32
  const float* bias = (const float*)d_in[2];   // (64, 1024) f32
  float*       out  = (float*)d_out;           // (256, 64, 1024) f32
  unsigned short* zs = (unsigned short*)d_ws;  // 16384*1024 fp16 = 33.5 MB

  sort_kernel<<<4096, 256, 0, stream>>>(x, zs);
  gemm_kernel<<<dim3(16, 64), 256, 0, stream>>>(zs, W, bias, out);
}

// Round 5
// 482.134 us; speedup vs baseline: 1.2270x; 1.1771x over previous
//
#include <hip/hip_runtime.h>

typedef _Float16 half8   __attribute__((ext_vector_type(8)));
typedef __fp16   half2_t __attribute__((ext_vector_type(2)));
typedef float    floatx4 __attribute__((ext_vector_type(4)));

__device__ inline void async_copy16(const void* g, void* l) {
  __builtin_amdgcn_global_load_lds(
      (const __attribute__((address_space(1))) unsigned int*)g,
      (__attribute__((address_space(3))) unsigned int*)l, 16, 0, 0);
}

// ---------------------------------------------------------------------------
// Kernel 1: sort each (n,c) 1024-vector descending, write fp16 to workspace.
// One wave per vector, 16 elems/lane, register bitonic (unchanged).
// ws layout: z[c][n][x], row = c*256 + n
// ---------------------------------------------------------------------------
__global__ __launch_bounds__(256) void sort_kernel(const float* __restrict__ x,
                                                   unsigned short* __restrict__ zs) {
  const int wave = threadIdx.x >> 6;
  const int lane = threadIdx.x & 63;
  const int vec  = (blockIdx.x << 2) + wave;     // vec = n*64 + c

  const float* src = x + ((size_t)vec << 10) + (lane << 4);
  float v[16];
#pragma unroll
  for (int r4 = 0; r4 < 4; ++r4) {
    float4 f = *reinterpret_cast<const float4*>(src + (r4 << 2));
    v[r4 * 4 + 0] = f.x; v[r4 * 4 + 1] = f.y;
    v[r4 * 4 + 2] = f.z; v[r4 * 4 + 3] = f.w;
  }

  auto CEs = [&](int a, int b, bool desc) {
    float lo = fminf(v[a], v[b]);
    float hi = fmaxf(v[a], v[b]);
    v[a] = desc ? hi : lo;
    v[b] = desc ? lo : hi;
  };

#pragma unroll
  for (int r = 0; r < 16; r += 2) CEs(r, r + 1, (r & 2) == 0);
#pragma unroll
  for (int r = 0; r < 16; ++r) if ((r & 2) == 0) CEs(r, r | 2, (r & 4) == 0);
#pragma unroll
  for (int r = 0; r < 16; r += 2) CEs(r, r + 1, (r & 4) == 0);
#pragma unroll
  for (int r = 0; r < 16; ++r) if ((r & 4) == 0) CEs(r, r | 4, (r & 8) == 0);
#pragma unroll
  for (int r = 0; r < 16; ++r) if ((r & 2) == 0) CEs(r, r | 2, (r & 8) == 0);
#pragma unroll
  for (int r = 0; r < 16; r += 2) CEs(r, r + 1, (r & 8) == 0);

#pragma unroll
  for (int k = 16; k <= 1024; k <<= 1) {
    const bool d = (lane & (k >> 4)) == 0;
#pragma unroll
    for (int j = k >> 1; j >= 16; j >>= 1) {
      const int dl = j >> 4;
      const bool keepmax = (((lane & dl) == 0) == d);
#pragma unroll
      for (int r = 0; r < 16; ++r) {
        float p = __shfl_xor(v[r], dl, 64);
        v[r] = keepmax ? fmaxf(v[r], p) : fminf(v[r], p);
      }
    }
#pragma unroll
    for (int j = 8; j >= 1; j >>= 1)
#pragma unroll
      for (int r = 0; r < 16; ++r)
        if ((r & j) == 0) CEs(r, r | j, d);
  }

  const int n = vec >> 6, c = vec & 63;
  union { half2_t h2[8]; uint4 u[2]; } pk;
#pragma unroll
  for (int r = 0; r < 8; ++r)
    pk.h2[r] = __builtin_amdgcn_cvt_pkrtz(v[2 * r], v[2 * r + 1]);
  uint4* dst = reinterpret_cast<uint4*>(zs + ((size_t)(c * 256 + n) << 10) + (lane << 4));
  dst[0] = pk.u[0];
  dst[1] = pk.u[1];
}

// ---------------------------------------------------------------------------
// Kernel 2: m97-style async-LDS GEMM.  grid=(16 n-slabs, 64 ch), 256 thr.
// Block tile M=256 (all batch rows of the channel) x N=64, BK=64.
// Staging via global_load_lds (no dest VGPRs -> scheduler can't serialize;
// R3/R4 showed register pipelines collapse to 1 load in flight).
// A: z fp16, LDS 256x64h (32KB), 8 chunks/row, chunk swizzle c^=(r&7) applied
//    at the GLOBAL address (LDS dst is fixed lane*16B).
// B: W f32 raw, LDS 64x64f (16KB), 16 chunks/row, swizzle c^=(o&7).
// Frag reads are then bank-balanced (8 words/bank minimum).
// Wave tile 64x64: 4x4 mfma_f32_16x16x32_f16 per ks, ks=0,1 per stage.
// W read exactly once from HBM; z re-reads (x16 slabs) hit L2.
// ---------------------------------------------------------------------------
__global__ __launch_bounds__(256) void gemm_kernel(const unsigned short* __restrict__ zs,
                                                   const float* __restrict__ W,
                                                   const float* __restrict__ bias,
                                                   float* __restrict__ out) {
  __shared__ unsigned short As[256 * 64];  // 32KB  [r][chunk^ (r&7)]
  __shared__ float          Bs[64 * 64];   // 16KB  [o][chunk^ (o&7)]

  const int c    = blockIdx.y;
  const int nt   = blockIdx.x;             // 64-col slab
  const int tid  = threadIdx.x;
  const int w    = tid >> 6, lane = tid & 63;
  const int lr   = lane & 15;
  const int q    = lane >> 4;

  const unsigned short* zc = zs + (((size_t)c * 256) << 10);
  const float*          wc = W + ((size_t)c << 20) + (((size_t)nt * 64) << 10);

  // staging lane geometry (kb-independent)
  const int a_lr8 = lane >> 3, a_ch = lane & 7;
  const int a_cs  = a_ch ^ a_lr8;                       // A source chunk
  const int b_lr4 = lane >> 4, b_ch = lane & 15;
  const int b_cs  = b_ch ^ ((4 * (w & 1) + b_lr4) & 7); // B source chunk

  floatx4 acc[4][4] = {};
  union U { uint4 u; half8 h; float4 f; };

  for (int kb = 0; kb < 1024; kb += 64) {
    // --- stage A: 8 wave-passes x 1KB (8 rows of 128B each) ---
#pragma unroll
    for (int p = 0; p < 8; ++p) {
      const int r0 = (p * 4 + w) * 8;                  // wave-uniform
      const unsigned short* g =
          zc + (((size_t)(r0 + a_lr8)) << 10) + kb + (a_cs << 3);
      async_copy16(g, &As[r0 << 6]);
    }
    // --- stage B: 4 wave-passes x 1KB (4 rows of 256B each) ---
#pragma unroll
    for (int p = 0; p < 4; ++p) {
      const int o0 = (p * 4 + w) * 4;                  // wave-uniform
      const float* g = wc + (((size_t)(o0 + b_lr4)) << 10) + kb + (b_cs << 2);
      async_copy16(g, &Bs[o0 << 6]);
    }
    __syncthreads();

#pragma unroll
    for (int ks = 0; ks < 2; ++ks) {
      half8 af[4];
#pragma unroll
      for (int mi = 0; mi < 4; ++mi) {
        const int r  = w * 64 + mi * 16 + lr;
        const int ch = (ks * 4 + q) ^ (r & 7);
        af[mi] = *reinterpret_cast<const half8*>(&As[(r << 6) + (ch << 3)]);
      }
#pragma unroll
      for (int ni = 0; ni < 4; ++ni) {
        const int o  = ni * 16 + lr;
        const int c0 = (ks * 8 + q * 2) ^ (o & 7);
        const int c1 = (ks * 8 + q * 2 + 1) ^ (o & 7);
        const float4 f0 = *reinterpret_cast<const float4*>(&Bs[(o << 6) + (c0 << 2)]);
        const float4 f1 = *reinterpret_cast<const float4*>(&Bs[(o << 6) + (c1 << 2)]);
        union { half2_t h2[4]; half8 h8; } pk;
        pk.h2[0] = __builtin_amdgcn_cvt_pkrtz(f0.x, f0.y);
        pk.h2[1] = __builtin_amdgcn_cvt_pkrtz(f0.z, f0.w);
        pk.h2[2] = __builtin_amdgcn_cvt_pkrtz(f1.x, f1.y);
        pk.h2[3] = __builtin_amdgcn_cvt_pkrtz(f1.z, f1.w);
#pragma unroll
        for (int mi = 0; mi < 4; ++mi)
          acc[mi][ni] =
              __builtin_amdgcn_mfma_f32_16x16x32_f16(af[mi], pk.h8, acc[mi][ni], 0, 0, 0);
      }
    }
    __syncthreads();
  }

  // epilogue: bias + sigmoid, out[n][c][o] fp32
#pragma unroll
  for (int ni = 0; ni < 4; ++ni) {
    const int col = nt * 64 + ni * 16 + lr;
    const float bv = bias[(c << 10) + col];
#pragma unroll
    for (int mi = 0; mi < 4; ++mi) {
      const int row0 = w * 64 + mi * 16 + q * 4;
#pragma unroll
      for (int rr = 0; rr < 4; ++rr) {
        const float y = acc[mi][ni][rr] + bv;
        const float s = __builtin_amdgcn_rcpf(1.0f + __expf(-y));
        out[(((size_t)(row0 + rr) << 6) + c) * 1024 + col] = s;
      }
    }
  }
}

extern "C" void kernel_launch(void* const* d_in, const int* in_sizes, int n_in,
                              void* d_out, int out_size, void* d_ws, size_t ws_size,
                              hipStream_t stream) {
  const float* x    = (const float*)d_in[0];   // (256, 64, 32, 32) f32
  const float* W    = (const float*)d_in[1];   // (64, 1024, 1024) f32
  const float* bias = (const float*)d_in[2];   // (64, 1024) f32
  float*       out  = (float*)d_out;           // (256, 64, 1024) f32
  unsigned short* zs = (unsigned short*)d_ws;  // 16384*1024 fp16 = 33.5 MB

  sort_kernel<<<4096, 256, 0, stream>>>(x, zs);
  gemm_kernel<<<dim3(16, 64), 256, 0, stream>>>(zs, W, bias, out);
}